// Round 2
// baseline (10636.875 us; speedup 1.0000x reference)
//
#include <hip/hip_runtime.h>
#include <hip/hip_bf16.h>
#include <hip/hip_cooperative_groups.h>

namespace cg = cooperative_groups;

typedef __attribute__((ext_vector_type(8))) short bf16x8;
typedef __attribute__((ext_vector_type(4))) float f32x4;

#define D_ 1024
#define T_ 1024
#define B_ 8
#define M_ (T_ * B_)

__device__ __forceinline__ float ldv(const float* p) { return *p; }
__device__ __forceinline__ float ldv(const __hip_bfloat16* p) { return __bfloat162float(*p); }
__device__ __forceinline__ void stv(float* p, float v) { *p = v; }
__device__ __forceinline__ void stv(__hip_bfloat16* p, float v) { *p = __float2bfloat16(v); }

// ---------------------------------------------------------------------------
// f32 -> bf16 bulk convert (8 elems/thread, vectorized)
// ---------------------------------------------------------------------------
__global__ __launch_bounds__(256) void conv_bf16(const float* __restrict__ in,
                                                 __hip_bfloat16* __restrict__ out,
                                                 int n8)
{
  int i = blockIdx.x * blockDim.x + threadIdx.x;
  const int stride = gridDim.x * blockDim.x;
  for (; i < n8; i += stride) {
    const f32x4* p = reinterpret_cast<const f32x4*>(in + (size_t)i * 8);
    f32x4 a = p[0], b = p[1];
    union { bf16x8 v; __hip_bfloat16 e[8]; } u;
#pragma unroll
    for (int j = 0; j < 4; ++j) {
      u.e[j] = __float2bfloat16(a[j]);
      u.e[j + 4] = __float2bfloat16(b[j]);
    }
    *reinterpret_cast<bf16x8*>(out + (size_t)i * 8) = u.v;
  }
}

// ---------------------------------------------------------------------------
// Phase 1: alpha_all = sigmoid(xb @ Wab^T + b_alpha), wx_all = xb @ Wxb^T + b
// M=8192 (t*8+b), N=1024, K=1024.  blockIdx.y<8 -> alpha GEMM, else wx GEMM.
// Block 256 thr = 4 waves (2x2), wave tile 64x64 (4x4 MFMA frags), no LDS.
// mfma_f32_16x16x32_bf16: A/B frag = lane(l): row l&15, k-off 8*(l>>4), 8 bf16.
// C/D: col = l&15, row = (l>>4)*4 + reg   [verified layout]
// ---------------------------------------------------------------------------
template <typename ST>
__global__ __launch_bounds__(256) void gemm_front(
    const __hip_bfloat16* __restrict__ xb,
    const __hip_bfloat16* __restrict__ Wab,
    const float* __restrict__ ba,
    const __hip_bfloat16* __restrict__ Wxb,
    const float* __restrict__ bbias,
    ST* __restrict__ alpha_out,
    ST* __restrict__ wx_out)
{
  const int tid = threadIdx.x;
  const int lane = tid & 63;
  const int w = tid >> 6;
  const int r = lane & 15;
  const int g = lane >> 4;
  const bool isA = blockIdx.y < 8;
  const int m0 = blockIdx.x * 128 + (w >> 1) * 64;
  const int n0 = (blockIdx.y & 7) * 128 + (w & 1) * 64;
  const __hip_bfloat16* __restrict__ W = isA ? Wab : Wxb;
  ST* __restrict__ outp = isA ? alpha_out : wx_out;

  f32x4 acc[4][4] = {};

  const __hip_bfloat16* aBase = xb + (size_t)(m0 + r) * D_ + g * 8;
  const __hip_bfloat16* bBase = W + (size_t)(n0 + r) * D_ + g * 8;

  for (int k = 0; k < D_; k += 32) {
    bf16x8 a[4], b[4];
#pragma unroll
    for (int mt = 0; mt < 4; ++mt)
      a[mt] = *reinterpret_cast<const bf16x8*>(aBase + (size_t)mt * 16 * D_ + k);
#pragma unroll
    for (int nt = 0; nt < 4; ++nt)
      b[nt] = *reinterpret_cast<const bf16x8*>(bBase + (size_t)nt * 16 * D_ + k);
#pragma unroll
    for (int mt = 0; mt < 4; ++mt)
#pragma unroll
      for (int nt = 0; nt < 4; ++nt)
        acc[mt][nt] = __builtin_amdgcn_mfma_f32_16x16x32_bf16(a[mt], b[nt], acc[mt][nt], 0, 0, 0);
  }

#pragma unroll
  for (int nt = 0; nt < 4; ++nt) {
    const int col = n0 + nt * 16 + r;
    const float bias = isA ? ba[col] : bbias[col];
#pragma unroll
    for (int mt = 0; mt < 4; ++mt) {
      const int row = m0 + mt * 16 + g * 4;
#pragma unroll
      for (int i = 0; i < 4; ++i) {
        float v = acc[mt][nt][i] + bias;
        if (isA) v = 1.0f / (1.0f + expf(-v));
        stv(outp + (size_t)(row + i) * D_ + col, v);
      }
    }
  }
}

// ---------------------------------------------------------------------------
// Phase 2: sequential scan.  Cooperative kernel, 64 WGs x 256 thr.
// WG owns cols e0..e0+15 (one 16-wide n-tile) for ALL 8 batches.
// W_h slice [16][1024] converted to bf16 in LDS (padded stride 1032).
// Per step: 4 waves split K (256 each), MFMA 16x16x32 with batch dim padded
// 8->16 (zero rows), partials reduced via LDS; finish phase (tid<128,
// thread=(b,cc)) carries h in f32 regs, writes bf16 h to ping-pong global
// hbuf + f32 outputs, then grid.sync().
// ---------------------------------------------------------------------------
template <typename ST>
__global__ __launch_bounds__(256) void scan_rec(
    const float* __restrict__ h0,
    const float* __restrict__ Wh,
    const ST* __restrict__ alpha_all,
    const ST* __restrict__ wx_all,
    __hip_bfloat16* __restrict__ hbuf,  // [2][B][D] ping-pong (bf16)
    float* __restrict__ out_outs,       // [T][B][D] f32
    float* __restrict__ out_h)          // [T+1][B][D] f32
{
  constexpr int WLD = 1032;  // padded LDS row stride (elements, 16B-aligned)
  __shared__ __align__(16) unsigned short W_lds[16 * WLD];
  __shared__ float C_lds[4][8][16];  // [wave][batch][col]

  const int tid = threadIdx.x;
  const int lane = tid & 63;
  const int w = tid >> 6;
  const int r = lane & 15;
  const int g = lane >> 4;
  const int e0 = blockIdx.x * 16;

  // Stage W_h rows e0..e0+15 into LDS as bf16 (f32 source, 32B chunks).
  for (int idx = tid; idx < 16 * 128; idx += 256) {
    const int row = idx >> 7;
    const int c8 = (idx & 127) * 8;
    const f32x4* p = reinterpret_cast<const f32x4*>(Wh + (size_t)(e0 + row) * D_ + c8);
    f32x4 a = p[0], b = p[1];
    union { bf16x8 v; __hip_bfloat16 e[8]; } u;
#pragma unroll
    for (int j = 0; j < 4; ++j) {
      u.e[j] = __float2bfloat16(a[j]);
      u.e[j + 4] = __float2bfloat16(b[j]);
    }
    *reinterpret_cast<bf16x8*>(&W_lds[row * WLD + c8]) = u.v;
  }

  const int b = tid >> 4;   // batch, valid for tid<128
  const int cc = tid & 15;  // col within tile
  const int e = e0 + cc;
  float h_f = 0.0f, wx_c = 0.0f, al_c = 0.0f;
  if (tid < 128) {
    h_f = h0[b * D_ + e];
    hbuf[b * D_ + e] = __float2bfloat16(h_f);  // ping buffer 0 = h0
    out_h[b * D_ + e] = h_f;                   // h output row t=0
    wx_c = ldv(wx_all + (size_t)b * D_ + e);
    al_c = ldv(alpha_all + (size_t)b * D_ + e);
  }

  cg::grid_group grid = cg::this_grid();
  grid.sync();  // publish hbuf[0]; also covers LDS staging barrier

  const int kbase = w * 256 + g * 8;
  for (int t = 0; t < T_; ++t) {
    const __hip_bfloat16* __restrict__ hc = hbuf + (size_t)(t & 1) * (B_ * D_);

    // Prefetch next step's wx/alpha (hidden under the MFMA phase).
    float wx_n = 0.0f, al_n = 0.0f;
    if (tid < 128 && t + 1 < T_) {
      wx_n = ldv(wx_all + (size_t)((t + 1) * B_ + b) * D_ + e);
      al_n = ldv(alpha_all + (size_t)((t + 1) * B_ + b) * D_ + e);
    }

    // MFMA phase: partial [8x16] over this wave's K quarter.
    f32x4 acc = {};
#pragma unroll
    for (int kt = 0; kt < 8; ++kt) {
      const int k = kbase + kt * 32;
      bf16x8 afrag = {};
      if (r < 8)  // batch rows 0..7 real, 8..15 zero-padded
        afrag = *reinterpret_cast<const bf16x8*>(hc + r * D_ + k);
      bf16x8 bfrag = *reinterpret_cast<const bf16x8*>(&W_lds[r * WLD + k]);
      acc = __builtin_amdgcn_mfma_f32_16x16x32_bf16(afrag, bfrag, acc, 0, 0, 0);
    }
    if (g < 2) {  // rows (g*4+i) in 0..7 are the real batches
#pragma unroll
      for (int i = 0; i < 4; ++i)
        C_lds[w][g * 4 + i][r] = acc[i];
    }
    __syncthreads();

    if (tid < 128) {
      const float vsum =
          C_lds[0][b][cc] + C_lds[1][b][cc] + C_lds[2][b][cc] + C_lds[3][b][cc];
      const float v = tanhf(vsum + wx_c);
      h_f = al_c * h_f + (1.0f - al_c) * v;  // f32-carried state
      const float sg = 1.0f / (1.0f + expf(-h_f));
      const float o = h_f * h_f * sg;  // h * silu(h)
      hbuf[(size_t)((t & 1) ^ 1) * (B_ * D_) + b * D_ + e] = __float2bfloat16(h_f);
      out_h[(size_t)(t + 1) * (B_ * D_) + b * D_ + e] = h_f;
      out_outs[(size_t)t * (B_ * D_) + b * D_ + e] = o;
      wx_c = wx_n;
      al_c = al_n;
    }
    grid.sync();  // publish hbuf[(t&1)^1] to all WGs
  }
}

// ---------------------------------------------------------------------------
template <typename ST>
static void launch_all(const float* x, const float* h0, const float* Wa,
                       const float* ba, const float* Wh, const float* Wx,
                       const float* bb, __hip_bfloat16* xb, __hip_bfloat16* Wab,
                       __hip_bfloat16* Wxb, ST* alpha_buf, ST* wx_buf,
                       __hip_bfloat16* hbuf, float* out_outs, float* out_h,
                       hipStream_t stream)
{
  conv_bf16<<<dim3(2048), dim3(256), 0, stream>>>(x, xb, M_ * D_ / 8);
  conv_bf16<<<dim3(512), dim3(256), 0, stream>>>(Wa, Wab, D_ * D_ / 8);
  conv_bf16<<<dim3(512), dim3(256), 0, stream>>>(Wx, Wxb, D_ * D_ / 8);
  gemm_front<ST><<<dim3(64, 16), dim3(256), 0, stream>>>(xb, Wab, ba, Wxb, bb,
                                                         alpha_buf, wx_buf);
  void* args[] = {(void*)&h0,     (void*)&Wh,   (void*)&alpha_buf,
                  (void*)&wx_buf, (void*)&hbuf, (void*)&out_outs,
                  (void*)&out_h};
  hipLaunchCooperativeKernel(reinterpret_cast<void*>(&scan_rec<ST>), dim3(64),
                             dim3(256), args, 0, stream);
}

extern "C" void kernel_launch(void* const* d_in, const int* in_sizes, int n_in,
                              void* d_out, int out_size, void* d_ws,
                              size_t ws_size, hipStream_t stream)
{
  const float* x = (const float*)d_in[0];
  const float* h0 = (const float*)d_in[1];
  const float* Wa = (const float*)d_in[2];
  const float* ba = (const float*)d_in[3];
  const float* Wh = (const float*)d_in[4];
  const float* Wx = (const float*)d_in[5];
  const float* bb = (const float*)d_in[6];

  float* out_outs = (float*)d_out;
  float* out_h = out_outs + (size_t)T_ * B_ * D_;

  char* ws = (char*)d_ws;
  const size_t nMD = (size_t)M_ * D_;   // 8,388,608
  const size_t nDD = (size_t)D_ * D_;   // 1,048,576

  __hip_bfloat16* xb = (__hip_bfloat16*)ws;                      // 16 MB
  __hip_bfloat16* Wab = (__hip_bfloat16*)(ws + nMD * 2);         // 2 MB
  __hip_bfloat16* Wxb = (__hip_bfloat16*)(ws + nMD * 2 + nDD * 2);
  char* rest = ws + nMD * 2 + 2 * nDD * 2;  // offset 20,971,520

  const size_t hbufBytes = (size_t)2 * B_ * D_ * sizeof(__hip_bfloat16);
  const size_t needF32 = (size_t)(rest - ws) + 2 * nMD * 4 + hbufBytes;

  if (ws_size >= needF32) {
    float* alpha_buf = (float*)rest;
    float* wx_buf = (float*)(rest + nMD * 4);
    __hip_bfloat16* hbuf = (__hip_bfloat16*)(rest + 2 * nMD * 4);
    launch_all<float>(x, h0, Wa, ba, Wh, Wx, bb, xb, Wab, Wxb, alpha_buf,
                      wx_buf, hbuf, out_outs, out_h, stream);
  } else {
    __hip_bfloat16* alpha_buf = (__hip_bfloat16*)rest;
    __hip_bfloat16* wx_buf = (__hip_bfloat16*)(rest + nMD * 2);
    __hip_bfloat16* hbuf = (__hip_bfloat16*)(rest + 2 * nMD * 2);
    launch_all<__hip_bfloat16>(x, h0, Wa, ba, Wh, Wx, bb, xb, Wab, Wxb,
                               alpha_buf, wx_buf, hbuf, out_outs, out_h,
                               stream);
  }
}

// Round 3
// 9777.697 us; speedup vs baseline: 1.0879x; 1.0879x over previous
//
#include <hip/hip_runtime.h>
#include <hip/hip_bf16.h>
#include <hip/hip_cooperative_groups.h>

typedef __attribute__((ext_vector_type(8))) short bf16x8;
typedef __attribute__((ext_vector_type(4))) float f32x4;

#define D_ 1024
#define T_ 1024
#define B_ 8
#define M_ (T_ * B_)

__device__ __forceinline__ float ldv(const float* p) { return *p; }
__device__ __forceinline__ float ldv(const __hip_bfloat16* p) { return __bfloat162float(*p); }
__device__ __forceinline__ void stv(float* p, float v) { *p = v; }
__device__ __forceinline__ void stv(__hip_bfloat16* p, float v) { *p = __float2bfloat16(v); }

// ---------------------------------------------------------------------------
// f32 -> bf16 bulk convert (8 elems/thread, vectorized)
// ---------------------------------------------------------------------------
__global__ __launch_bounds__(256) void conv_bf16(const float* __restrict__ in,
                                                 __hip_bfloat16* __restrict__ out,
                                                 int n8)
{
  int i = blockIdx.x * blockDim.x + threadIdx.x;
  const int stride = gridDim.x * blockDim.x;
  for (; i < n8; i += stride) {
    const f32x4* p = reinterpret_cast<const f32x4*>(in + (size_t)i * 8);
    f32x4 a = p[0], b = p[1];
    union { bf16x8 v; __hip_bfloat16 e[8]; } u;
#pragma unroll
    for (int j = 0; j < 4; ++j) {
      u.e[j] = __float2bfloat16(a[j]);
      u.e[j + 4] = __float2bfloat16(b[j]);
    }
    *reinterpret_cast<bf16x8*>(out + (size_t)i * 8) = u.v;
  }
}

// ---------------------------------------------------------------------------
// Phase 1: alpha_all = sigmoid(xb @ Wab^T + b_alpha), wx_all = xb @ Wxb^T + b
// (unchanged from round 2 — verified correct)
// ---------------------------------------------------------------------------
template <typename ST>
__global__ __launch_bounds__(256) void gemm_front(
    const __hip_bfloat16* __restrict__ xb,
    const __hip_bfloat16* __restrict__ Wab,
    const float* __restrict__ ba,
    const __hip_bfloat16* __restrict__ Wxb,
    const float* __restrict__ bbias,
    ST* __restrict__ alpha_out,
    ST* __restrict__ wx_out)
{
  const int tid = threadIdx.x;
  const int lane = tid & 63;
  const int w = tid >> 6;
  const int r = lane & 15;
  const int g = lane >> 4;
  const bool isA = blockIdx.y < 8;
  const int m0 = blockIdx.x * 128 + (w >> 1) * 64;
  const int n0 = (blockIdx.y & 7) * 128 + (w & 1) * 64;
  const __hip_bfloat16* __restrict__ W = isA ? Wab : Wxb;
  ST* __restrict__ outp = isA ? alpha_out : wx_out;

  f32x4 acc[4][4] = {};

  const __hip_bfloat16* aBase = xb + (size_t)(m0 + r) * D_ + g * 8;
  const __hip_bfloat16* bBase = W + (size_t)(n0 + r) * D_ + g * 8;

  for (int k = 0; k < D_; k += 32) {
    bf16x8 a[4], b[4];
#pragma unroll
    for (int mt = 0; mt < 4; ++mt)
      a[mt] = *reinterpret_cast<const bf16x8*>(aBase + (size_t)mt * 16 * D_ + k);
#pragma unroll
    for (int nt = 0; nt < 4; ++nt)
      b[nt] = *reinterpret_cast<const bf16x8*>(bBase + (size_t)nt * 16 * D_ + k);
#pragma unroll
    for (int mt = 0; mt < 4; ++mt)
#pragma unroll
      for (int nt = 0; nt < 4; ++nt)
        acc[mt][nt] = __builtin_amdgcn_mfma_f32_16x16x32_bf16(a[mt], b[nt], acc[mt][nt], 0, 0, 0);
  }

#pragma unroll
  for (int nt = 0; nt < 4; ++nt) {
    const int col = n0 + nt * 16 + r;
    const float bias = isA ? ba[col] : bbias[col];
#pragma unroll
    for (int mt = 0; mt < 4; ++mt) {
      const int row = m0 + mt * 16 + g * 4;
#pragma unroll
      for (int i = 0; i < 4; ++i) {
        float v = acc[mt][nt][i] + bias;
        if (isA) v = 1.0f / (1.0f + expf(-v));
        stv(outp + (size_t)(row + i) * D_ + col, v);
      }
    }
  }
}

// ---------------------------------------------------------------------------
// Phase 2: scan via batch-independent islands + p2p flag sync (no barrier).
// Grid 128 WGs x 256 thr: WG = (batch b = blockIdx.x>>4, slice s = &15).
// WG owns output cols [s*64, s*64+64) of batch b; W_h slice [64][1024] bf16
// in LDS, XOR-swizzled (byte ^= (row&7)<<4) for conflict-free b128 reads.
// h exchanged via depth-2 f32 ring in global (agent-scope atomics);
// flag[b*16+s] = t+2 published after h[t+1] slice stored (release, agent).
// Wave w covers K quarter [w*256,+256) -> polls only its 4 producers.
// Own slice short-circuits through LDS (finish writes h_lds directly).
// ---------------------------------------------------------------------------
template <typename ST>
__global__ __launch_bounds__(256) void scan_rec(
    const float* __restrict__ h0,
    const float* __restrict__ Wh,
    const ST* __restrict__ alpha_all,
    const ST* __restrict__ wx_all,
    float* __restrict__ ring,          // [2][B][D] f32, agent-coherent
    unsigned int* __restrict__ flags,  // [B*16], memset 0 per call
    float* __restrict__ out_outs,      // [T][B][D] f32
    float* __restrict__ out_h)         // [T+1][B][D] f32
{
  __shared__ __align__(16) unsigned short W_lds[64 * 1024];  // 128 KB, swizzled
  __shared__ __align__(16) unsigned short h_lds[1024];       // h[t] bf16
  __shared__ float C_lds[4][64];                             // per-wave partials

  const int tid = threadIdx.x;
  const int lane = tid & 63;
  const int w = tid >> 6;
  const int r = lane & 15;
  const int g = lane >> 4;
  const int bb = blockIdx.x >> 4;  // batch
  const int s = blockIdx.x & 15;   // col slice
  const int e0 = s * 64;

  // ---- Stage W_h rows e0..e0+63 into LDS as bf16, XOR-swizzled ----
  for (int idx = tid; idx < 64 * 128; idx += 256) {
    const int row = idx >> 7;        // 0..63
    const int k8 = (idx & 127) * 8;  // k chunk start
    const f32x4* p = reinterpret_cast<const f32x4*>(Wh + (size_t)(e0 + row) * D_ + k8);
    f32x4 a = p[0], bv = p[1];
    union { bf16x8 v; __hip_bfloat16 e[8]; } u;
#pragma unroll
    for (int j = 0; j < 4; ++j) {
      u.e[j] = __float2bfloat16(a[j]);
      u.e[j + 4] = __float2bfloat16(bv[j]);
    }
    const unsigned byteoff = ((unsigned)row * 2048u + (unsigned)k8 * 2u) ^ (((unsigned)row & 7u) << 4);
    *reinterpret_cast<bf16x8*>(reinterpret_cast<char*>(W_lds) + byteoff) = u.v;
  }

  // ---- Init: finish threads (= wave 0, c = tid) own col e0+c ----
  float h_f = 0.0f, wx_c = 0.0f, al_c = 0.0f;
  if (tid < 64) {
    const int e = e0 + tid;
    h_f = h0[bb * D_ + e];
    out_h[(size_t)bb * D_ + e] = h_f;
    h_lds[e] = ((__hip_bfloat16_raw)__float2bfloat16(h_f)).x;
    __hip_atomic_store(&ring[(size_t)bb * D_ + e], h_f,
                       __ATOMIC_RELAXED, __HIP_MEMORY_SCOPE_AGENT);
    wx_c = ldv(wx_all + (size_t)bb * D_ + e);
    al_c = ldv(alpha_all + (size_t)bb * D_ + e);
  }
  __syncthreads();  // W_lds + h_lds ready; ring stores drained (vmcnt 0)
  if (tid == 0)
    __hip_atomic_store(&flags[bb * 16 + s], 1u,
                       __ATOMIC_RELEASE, __HIP_MEMORY_SCOPE_AGENT);

  const unsigned myflag = (unsigned)(bb * 16 + s);

  for (int t = 0; t < T_; ++t) {
    // ---- per-wave poll: the 4 producers covering k in [w*256, +256) ----
    const unsigned want = (unsigned)(t + 1);
    const int sp = w * 4 + lane;  // producer id for lanes 0..3
    for (;;) {
      int pred = 1;
      if (lane < 4 && sp != s) {
        unsigned f = __hip_atomic_load(&flags[bb * 16 + sp],
                                       __ATOMIC_ACQUIRE, __HIP_MEMORY_SCOPE_AGENT);
        pred = (f >= want);
      }
      if (__all(pred)) break;
      __builtin_amdgcn_s_sleep(1);
    }

    // ---- stage h[t] quarter into h_lds (skip own slice: already in LDS) ----
    {
      const int kk = w * 256 + lane * 4;  // 4 f32 per lane
      if ((kk >> 6) != s) {
        const float* rp = ring + (size_t)(t & 1) * (B_ * D_) + (size_t)bb * D_ + kk;
        float v0 = __hip_atomic_load(rp + 0, __ATOMIC_RELAXED, __HIP_MEMORY_SCOPE_AGENT);
        float v1 = __hip_atomic_load(rp + 1, __ATOMIC_RELAXED, __HIP_MEMORY_SCOPE_AGENT);
        float v2 = __hip_atomic_load(rp + 2, __ATOMIC_RELAXED, __HIP_MEMORY_SCOPE_AGENT);
        float v3 = __hip_atomic_load(rp + 3, __ATOMIC_RELAXED, __HIP_MEMORY_SCOPE_AGENT);
        union { unsigned long long q; unsigned short e[4]; } u;
        u.e[0] = ((__hip_bfloat16_raw)__float2bfloat16(v0)).x;
        u.e[1] = ((__hip_bfloat16_raw)__float2bfloat16(v1)).x;
        u.e[2] = ((__hip_bfloat16_raw)__float2bfloat16(v2)).x;
        u.e[3] = ((__hip_bfloat16_raw)__float2bfloat16(v3)).x;
        *reinterpret_cast<unsigned long long*>(&h_lds[kk]) = u.q;
      }
    }
    asm volatile("s_waitcnt lgkmcnt(0)" ::: "memory");
    __builtin_amdgcn_sched_barrier(0);

    // ---- MFMA: y_partial[64] over this wave's K quarter ----
    f32x4 acc[4] = {};
#pragma unroll
    for (int kt = 0; kt < 8; ++kt) {
      const int k = w * 256 + kt * 32 + g * 8;
      bf16x8 afrag = {};
      if (r == 0)
        afrag = *reinterpret_cast<const bf16x8*>(&h_lds[k]);
#pragma unroll
      for (int nt = 0; nt < 4; ++nt) {
        const unsigned row = (unsigned)(nt * 16 + r);
        const unsigned byteoff = (row * 2048u + (unsigned)k * 2u) ^ ((row & 7u) << 4);
        bf16x8 bfrag = *reinterpret_cast<const bf16x8*>(
            reinterpret_cast<const char*>(W_lds) + byteoff);
        acc[nt] = __builtin_amdgcn_mfma_f32_16x16x32_bf16(afrag, bfrag, acc[nt], 0, 0, 0);
      }
    }
    if (g == 0) {
#pragma unroll
      for (int nt = 0; nt < 4; ++nt)
        C_lds[w][nt * 16 + r] = acc[nt][0];
    }
    __syncthreads();

    // ---- finish (wave 0): y sum, recurrence, outputs, ring publish ----
    if (tid < 64) {
      const int e = e0 + tid;
      const float y = C_lds[0][tid] + C_lds[1][tid] + C_lds[2][tid] + C_lds[3][tid];
      const float v = tanhf(y + wx_c);
      h_f = al_c * h_f + (1.0f - al_c) * v;
      const float sg = 1.0f / (1.0f + expf(-h_f));
      const float o = h_f * h_f * sg;  // h * silu(h)
      // own slice -> LDS for next step (short-circuit)
      h_lds[e] = ((__hip_bfloat16_raw)__float2bfloat16(h_f)).x;
      // publish to ring (agent-coherent)
      __hip_atomic_store(&ring[(size_t)((t + 1) & 1) * (B_ * D_) + (size_t)bb * D_ + e],
                         h_f, __ATOMIC_RELAXED, __HIP_MEMORY_SCOPE_AGENT);
      out_h[(size_t)(t + 1) * (B_ * D_) + (size_t)bb * D_ + e] = h_f;
      out_outs[(size_t)t * (B_ * D_) + (size_t)bb * D_ + e] = o;
      // prefetch next step's wx/alpha (in flight during next poll)
      if (t + 1 < T_) {
        wx_c = ldv(wx_all + (size_t)((t + 1) * B_ + bb) * D_ + e);
        al_c = ldv(alpha_all + (size_t)((t + 1) * B_ + bb) * D_ + e);
      }
    }
    __syncthreads();  // drains vmcnt: ring stores done; orders C_lds/h_lds reuse
    if (tid == 0)
      __hip_atomic_store(&flags[myflag], (unsigned)(t + 2),
                         __ATOMIC_RELEASE, __HIP_MEMORY_SCOPE_AGENT);
  }
}

// ---------------------------------------------------------------------------
template <typename ST>
static void launch_all(const float* x, const float* h0, const float* Wa,
                       const float* ba, const float* Wh, const float* Wx,
                       const float* bb, __hip_bfloat16* xb, __hip_bfloat16* Wab,
                       __hip_bfloat16* Wxb, ST* alpha_buf, ST* wx_buf,
                       float* ring, unsigned int* flags, float* out_outs,
                       float* out_h, hipStream_t stream)
{
  hipMemsetAsync(flags, 0, B_ * 16 * sizeof(unsigned int), stream);
  conv_bf16<<<dim3(2048), dim3(256), 0, stream>>>(x, xb, M_ * D_ / 8);
  conv_bf16<<<dim3(512), dim3(256), 0, stream>>>(Wa, Wab, D_ * D_ / 8);
  conv_bf16<<<dim3(512), dim3(256), 0, stream>>>(Wx, Wxb, D_ * D_ / 8);
  gemm_front<ST><<<dim3(64, 16), dim3(256), 0, stream>>>(xb, Wab, ba, Wxb, bb,
                                                         alpha_buf, wx_buf);
  void* args[] = {(void*)&h0,     (void*)&Wh,    (void*)&alpha_buf,
                  (void*)&wx_buf, (void*)&ring,  (void*)&flags,
                  (void*)&out_outs, (void*)&out_h};
  hipLaunchCooperativeKernel(reinterpret_cast<void*>(&scan_rec<ST>), dim3(128),
                             dim3(256), args, 0, stream);
}

extern "C" void kernel_launch(void* const* d_in, const int* in_sizes, int n_in,
                              void* d_out, int out_size, void* d_ws,
                              size_t ws_size, hipStream_t stream)
{
  const float* x = (const float*)d_in[0];
  const float* h0 = (const float*)d_in[1];
  const float* Wa = (const float*)d_in[2];
  const float* ba = (const float*)d_in[3];
  const float* Wh = (const float*)d_in[4];
  const float* Wx = (const float*)d_in[5];
  const float* bb = (const float*)d_in[6];

  float* out_outs = (float*)d_out;
  float* out_h = out_outs + (size_t)T_ * B_ * D_;

  char* ws = (char*)d_ws;
  const size_t nMD = (size_t)M_ * D_;  // 8,388,608
  const size_t nDD = (size_t)D_ * D_;  // 1,048,576

  __hip_bfloat16* xb = (__hip_bfloat16*)ws;
  __hip_bfloat16* Wab = (__hip_bfloat16*)(ws + nMD * 2);
  __hip_bfloat16* Wxb = (__hip_bfloat16*)(ws + nMD * 2 + nDD * 2);
  char* rest = ws + nMD * 2 + 2 * nDD * 2;

  const size_t ringBytes = (size_t)2 * B_ * D_ * sizeof(float);
  const size_t flagBytes = (size_t)B_ * 16 * sizeof(unsigned int);
  const size_t needF32 =
      (size_t)(rest - ws) + 2 * nMD * 4 + ringBytes + flagBytes;

  if (ws_size >= needF32) {
    float* alpha_buf = (float*)rest;
    float* wx_buf = (float*)(rest + nMD * 4);
    float* ring = (float*)(rest + 2 * nMD * 4);
    unsigned int* flags = (unsigned int*)(rest + 2 * nMD * 4 + ringBytes);
    launch_all<float>(x, h0, Wa, ba, Wh, Wx, bb, xb, Wab, Wxb, alpha_buf,
                      wx_buf, ring, flags, out_outs, out_h, stream);
  } else {
    __hip_bfloat16* alpha_buf = (__hip_bfloat16*)rest;
    __hip_bfloat16* wx_buf = (__hip_bfloat16*)(rest + nMD * 2);
    float* ring = (float*)(rest + 2 * nMD * 2);
    unsigned int* flags = (unsigned int*)(rest + 2 * nMD * 2 + ringBytes);
    launch_all<__hip_bfloat16>(x, h0, Wa, ba, Wh, Wx, bb, xb, Wab, Wxb,
                               alpha_buf, wx_buf, ring, flags, out_outs, out_h,
                               stream);
  }
}

// Round 4
// 3260.413 us; speedup vs baseline: 3.2624x; 2.9989x over previous
//
#include <hip/hip_runtime.h>
#include <hip/hip_bf16.h>
#include <hip/hip_cooperative_groups.h>

typedef __attribute__((ext_vector_type(8))) short bf16x8;
typedef __attribute__((ext_vector_type(4))) float f32x4;
typedef __attribute__((ext_vector_type(4))) unsigned int u32x4;

#define D_ 1024
#define T_ 1024
#define B_ 8
#define M_ (T_ * B_)

__device__ __forceinline__ float ldv(const float* p) { return *p; }
__device__ __forceinline__ float ldv(const __hip_bfloat16* p) { return __bfloat162float(*p); }
__device__ __forceinline__ void stv(float* p, float v) { *p = v; }
__device__ __forceinline__ void stv(__hip_bfloat16* p, float v) { *p = __float2bfloat16(v); }

// --- MALL-coherent (L1/L2-bypassing) accessors: sc0 sc1, relaxed ----------
__device__ __forceinline__ unsigned ld_flag_mall(const unsigned* p) {
  unsigned v;
  asm volatile("global_load_dword %0, %1, off sc0 sc1\n\ts_waitcnt vmcnt(0)"
               : "=v"(v) : "v"(p) : "memory");
  return v;
}
__device__ __forceinline__ void st_u32_mall(unsigned* p, unsigned v) {
  asm volatile("global_store_dword %0, %1, off sc0 sc1" :: "v"(p), "v"(v) : "memory");
}
__device__ __forceinline__ u32x4 ld_b128_mall(const void* p) {
  u32x4 v;
  asm volatile("global_load_dwordx4 %0, %1, off sc0 sc1" : "=v"(v) : "v"(p) : "memory");
  return v;
}
__device__ __forceinline__ void wait_vm0() {
  asm volatile("s_waitcnt vmcnt(0)" ::: "memory");
}

// ---------------------------------------------------------------------------
// f32 -> bf16 bulk convert (8 elems/thread, vectorized)
// ---------------------------------------------------------------------------
__global__ __launch_bounds__(256) void conv_bf16(const float* __restrict__ in,
                                                 __hip_bfloat16* __restrict__ out,
                                                 int n8)
{
  int i = blockIdx.x * blockDim.x + threadIdx.x;
  const int stride = gridDim.x * blockDim.x;
  for (; i < n8; i += stride) {
    const f32x4* p = reinterpret_cast<const f32x4*>(in + (size_t)i * 8);
    f32x4 a = p[0], b = p[1];
    union { bf16x8 v; __hip_bfloat16 e[8]; } u;
#pragma unroll
    for (int j = 0; j < 4; ++j) {
      u.e[j] = __float2bfloat16(a[j]);
      u.e[j + 4] = __float2bfloat16(b[j]);
    }
    *reinterpret_cast<bf16x8*>(out + (size_t)i * 8) = u.v;
  }
}

// ---------------------------------------------------------------------------
// Phase 1: alpha_all = sigmoid(xb @ Wab^T + b_alpha), wx_all = xb @ Wxb^T + b
// (unchanged — verified correct)
// ---------------------------------------------------------------------------
template <typename ST>
__global__ __launch_bounds__(256) void gemm_front(
    const __hip_bfloat16* __restrict__ xb,
    const __hip_bfloat16* __restrict__ Wab,
    const float* __restrict__ ba,
    const __hip_bfloat16* __restrict__ Wxb,
    const float* __restrict__ bbias,
    ST* __restrict__ alpha_out,
    ST* __restrict__ wx_out)
{
  const int tid = threadIdx.x;
  const int lane = tid & 63;
  const int w = tid >> 6;
  const int r = lane & 15;
  const int g = lane >> 4;
  const bool isA = blockIdx.y < 8;
  const int m0 = blockIdx.x * 128 + (w >> 1) * 64;
  const int n0 = (blockIdx.y & 7) * 128 + (w & 1) * 64;
  const __hip_bfloat16* __restrict__ W = isA ? Wab : Wxb;
  ST* __restrict__ outp = isA ? alpha_out : wx_out;

  f32x4 acc[4][4] = {};

  const __hip_bfloat16* aBase = xb + (size_t)(m0 + r) * D_ + g * 8;
  const __hip_bfloat16* bBase = W + (size_t)(n0 + r) * D_ + g * 8;

  for (int k = 0; k < D_; k += 32) {
    bf16x8 a[4], b[4];
#pragma unroll
    for (int mt = 0; mt < 4; ++mt)
      a[mt] = *reinterpret_cast<const bf16x8*>(aBase + (size_t)mt * 16 * D_ + k);
#pragma unroll
    for (int nt = 0; nt < 4; ++nt)
      b[nt] = *reinterpret_cast<const bf16x8*>(bBase + (size_t)nt * 16 * D_ + k);
#pragma unroll
    for (int mt = 0; mt < 4; ++mt)
#pragma unroll
      for (int nt = 0; nt < 4; ++nt)
        acc[mt][nt] = __builtin_amdgcn_mfma_f32_16x16x32_bf16(a[mt], b[nt], acc[mt][nt], 0, 0, 0);
  }

#pragma unroll
  for (int nt = 0; nt < 4; ++nt) {
    const int col = n0 + nt * 16 + r;
    const float bias = isA ? ba[col] : bbias[col];
#pragma unroll
    for (int mt = 0; mt < 4; ++mt) {
      const int row = m0 + mt * 16 + g * 4;
#pragma unroll
      for (int i = 0; i < 4; ++i) {
        float v = acc[mt][nt][i] + bias;
        if (isA) v = 1.0f / (1.0f + expf(-v));
        stv(outp + (size_t)(row + i) * D_ + col, v);
      }
    }
  }
}

// ---------------------------------------------------------------------------
// Phase 2: scan via batch-islands + relaxed MALL message passing (no fences).
// Grid 128 WGs x 256 thr: WG = (batch b = blockIdx.x>>4, slice s = &15).
// ring: [2][B][D] bf16 (packed pairs), flags[B*16] monotone (t+2).
// All ring/flag traffic via sc0-sc1 bypass ops; ordering via vmcnt(0) only.
// Depth-2 reuse safe: finish runs after __syncthreads => all 16 flags >= t+1
// observed before slot (t+1)&1 is overwritten.
// ---------------------------------------------------------------------------
template <typename ST>
__global__ __launch_bounds__(256) void scan_rec(
    const float* __restrict__ h0,
    const float* __restrict__ Wh,
    const ST* __restrict__ alpha_all,
    const ST* __restrict__ wx_all,
    unsigned short* __restrict__ ring,  // [2][B][D] bf16
    unsigned int* __restrict__ flags,   // [B*16], memset 0 per call
    float* __restrict__ out_outs,       // [T][B][D] f32
    float* __restrict__ out_h)          // [T+1][B][D] f32
{
  __shared__ __align__(16) unsigned short W_lds[64 * 1024];  // 128 KB, swizzled
  __shared__ __align__(16) unsigned short h_lds[1024];       // h[t] bf16
  __shared__ float C_lds[4][64];                             // per-wave partials

  const int tid = threadIdx.x;
  const int lane = tid & 63;
  const int w = tid >> 6;
  const int r = lane & 15;
  const int g = lane >> 4;
  const int bb = blockIdx.x >> 4;  // batch
  const int s = blockIdx.x & 15;   // col slice
  const int e0 = s * 64;

  // ---- Stage W_h rows e0..e0+63 into LDS as bf16, XOR-swizzled ----
  for (int idx = tid; idx < 64 * 128; idx += 256) {
    const int row = idx >> 7;        // 0..63
    const int k8 = (idx & 127) * 8;  // k chunk start
    const f32x4* p = reinterpret_cast<const f32x4*>(Wh + (size_t)(e0 + row) * D_ + k8);
    f32x4 a = p[0], bv = p[1];
    union { bf16x8 v; __hip_bfloat16 e[8]; } u;
#pragma unroll
    for (int j = 0; j < 4; ++j) {
      u.e[j] = __float2bfloat16(a[j]);
      u.e[j + 4] = __float2bfloat16(bv[j]);
    }
    const unsigned byteoff = ((unsigned)row * 2048u + (unsigned)k8 * 2u) ^ (((unsigned)row & 7u) << 4);
    *reinterpret_cast<bf16x8*>(reinterpret_cast<char*>(W_lds) + byteoff) = u.v;
  }

  // ---- Init: finish threads (wave 0, col e0+tid) ----
  float h_f = 0.0f, wx_c = 0.0f, al_c = 0.0f;
  if (tid < 64) {
    const int e = e0 + tid;
    h_f = h0[bb * D_ + e];
    out_h[(size_t)bb * D_ + e] = h_f;
    const unsigned short hb = ((__hip_bfloat16_raw)__float2bfloat16(h_f)).x;
    h_lds[e] = hb;
    // pack pair {even, odd} -> u32, even lanes store to ring slot 0
    const float hp = __shfl_xor(h_f, 1);
    const unsigned short pb = ((__hip_bfloat16_raw)__float2bfloat16(hp)).x;
    if (!(tid & 1)) {
      const unsigned word = (unsigned)hb | ((unsigned)pb << 16);
      st_u32_mall(reinterpret_cast<unsigned*>(ring + (size_t)bb * D_ + e), word);
    }
    wx_c = ldv(wx_all + (size_t)bb * D_ + e);
    al_c = ldv(alpha_all + (size_t)bb * D_ + e);
  }
  __syncthreads();  // W_lds/h_lds staged
  wait_vm0();       // wave0's ring stores ACKed at MALL
  if (tid == 0)
    st_u32_mall(&flags[bb * 16 + s], 1u);

  const int myflag = bb * 16 + s;

  for (int t = 0; t < T_; ++t) {
    // ---- per-wave poll (lanes 0..3): producers of this wave's K quarter ----
    const unsigned want = (unsigned)(t + 1);
    const int sp = w * 4 + lane;
    if (lane < 4 && sp != s) {
      const unsigned* fp = &flags[bb * 16 + sp];
      while (ld_flag_mall(fp) < want) {}
    }
    __builtin_amdgcn_sched_barrier(0);

    // ---- stage h[t] quarter into h_lds (lanes 0..31, 8 bf16 each) ----
    {
      const int kk = w * 256 + lane * 8;
      if (lane < 32 && (kk >> 6) != s) {
        const unsigned short* rp =
            ring + (size_t)(t & 1) * (B_ * D_) + (size_t)bb * D_ + kk;
        u32x4 pv = ld_b128_mall(rp);
        wait_vm0();
        *reinterpret_cast<u32x4*>(&h_lds[kk]) = pv;
      }
    }
    asm volatile("s_waitcnt lgkmcnt(0)" ::: "memory");
    __builtin_amdgcn_sched_barrier(0);

    // ---- MFMA: y_partial[64] over this wave's K quarter ----
    f32x4 acc[4] = {};
#pragma unroll
    for (int kt = 0; kt < 8; ++kt) {
      const int k = w * 256 + kt * 32 + g * 8;
      bf16x8 afrag = {};
      if (r == 0)
        afrag = *reinterpret_cast<const bf16x8*>(&h_lds[k]);
#pragma unroll
      for (int nt = 0; nt < 4; ++nt) {
        const unsigned row = (unsigned)(nt * 16 + r);
        const unsigned byteoff = (row * 2048u + (unsigned)k * 2u) ^ ((row & 7u) << 4);
        bf16x8 bfrag = *reinterpret_cast<const bf16x8*>(
            reinterpret_cast<const char*>(W_lds) + byteoff);
        acc[nt] = __builtin_amdgcn_mfma_f32_16x16x32_bf16(afrag, bfrag, acc[nt], 0, 0, 0);
      }
    }
    if (g == 0) {
#pragma unroll
      for (int nt = 0; nt < 4; ++nt)
        C_lds[w][nt * 16 + r] = acc[nt][0];
    }
    __syncthreads();

    // ---- finish (wave 0): recurrence; ring+flag FIRST, outputs after ----
    if (tid < 64) {
      const int e = e0 + tid;
      const float y = C_lds[0][tid] + C_lds[1][tid] + C_lds[2][tid] + C_lds[3][tid];
      const float v = tanhf(y + wx_c);
      h_f = al_c * h_f + (1.0f - al_c) * v;
      const unsigned short hb = ((__hip_bfloat16_raw)__float2bfloat16(h_f)).x;
      h_lds[e] = hb;  // own slice short-circuit for next step
      const float hp = __shfl_xor(h_f, 1);
      const unsigned short pb = ((__hip_bfloat16_raw)__float2bfloat16(hp)).x;
      if (!(tid & 1)) {
        const unsigned word = (unsigned)hb | ((unsigned)pb << 16);
        st_u32_mall(reinterpret_cast<unsigned*>(
                        ring + (size_t)((t + 1) & 1) * (B_ * D_) + (size_t)bb * D_ + e),
                    word);
      }
      wait_vm0();  // ring stores at MALL before flag
      if (tid == 0)
        st_u32_mall(&flags[myflag], (unsigned)(t + 2));
      // off-chain work after the flag:
      const float sg = 1.0f / (1.0f + expf(-h_f));
      const float o = h_f * h_f * sg;  // h * silu(h)
      out_h[(size_t)(t + 1) * (B_ * D_) + (size_t)bb * D_ + e] = h_f;
      out_outs[(size_t)t * (B_ * D_) + (size_t)bb * D_ + e] = o;
      if (t + 1 < T_) {
        wx_c = ldv(wx_all + (size_t)((t + 1) * B_ + bb) * D_ + e);
        al_c = ldv(alpha_all + (size_t)((t + 1) * B_ + bb) * D_ + e);
      }
    }
    __syncthreads();  // h_lds(own slice) visible to all; C_lds reusable
  }
}

// ---------------------------------------------------------------------------
template <typename ST>
static void launch_all(const float* x, const float* h0, const float* Wa,
                       const float* ba, const float* Wh, const float* Wx,
                       const float* bb, __hip_bfloat16* xb, __hip_bfloat16* Wab,
                       __hip_bfloat16* Wxb, ST* alpha_buf, ST* wx_buf,
                       unsigned short* ring, unsigned int* flags,
                       float* out_outs, float* out_h, hipStream_t stream)
{
  hipMemsetAsync(flags, 0, B_ * 16 * sizeof(unsigned int), stream);
  conv_bf16<<<dim3(2048), dim3(256), 0, stream>>>(x, xb, M_ * D_ / 8);
  conv_bf16<<<dim3(512), dim3(256), 0, stream>>>(Wa, Wab, D_ * D_ / 8);
  conv_bf16<<<dim3(512), dim3(256), 0, stream>>>(Wx, Wxb, D_ * D_ / 8);
  gemm_front<ST><<<dim3(64, 16), dim3(256), 0, stream>>>(xb, Wab, ba, Wxb, bb,
                                                         alpha_buf, wx_buf);
  void* args[] = {(void*)&h0,     (void*)&Wh,    (void*)&alpha_buf,
                  (void*)&wx_buf, (void*)&ring,  (void*)&flags,
                  (void*)&out_outs, (void*)&out_h};
  hipLaunchCooperativeKernel(reinterpret_cast<void*>(&scan_rec<ST>), dim3(128),
                             dim3(256), args, 0, stream);
}

extern "C" void kernel_launch(void* const* d_in, const int* in_sizes, int n_in,
                              void* d_out, int out_size, void* d_ws,
                              size_t ws_size, hipStream_t stream)
{
  const float* x = (const float*)d_in[0];
  const float* h0 = (const float*)d_in[1];
  const float* Wa = (const float*)d_in[2];
  const float* ba = (const float*)d_in[3];
  const float* Wh = (const float*)d_in[4];
  const float* Wx = (const float*)d_in[5];
  const float* bb = (const float*)d_in[6];

  float* out_outs = (float*)d_out;
  float* out_h = out_outs + (size_t)T_ * B_ * D_;

  char* ws = (char*)d_ws;
  const size_t nMD = (size_t)M_ * D_;  // 8,388,608
  const size_t nDD = (size_t)D_ * D_;  // 1,048,576

  __hip_bfloat16* xb = (__hip_bfloat16*)ws;
  __hip_bfloat16* Wab = (__hip_bfloat16*)(ws + nMD * 2);
  __hip_bfloat16* Wxb = (__hip_bfloat16*)(ws + nMD * 2 + nDD * 2);
  char* rest = ws + nMD * 2 + 2 * nDD * 2;

  const size_t ringBytes = (size_t)2 * B_ * D_ * sizeof(unsigned short);
  const size_t flagBytes = (size_t)B_ * 16 * sizeof(unsigned int);
  const size_t needF32 =
      (size_t)(rest - ws) + 2 * nMD * 4 + ringBytes + flagBytes;

  if (ws_size >= needF32) {
    float* alpha_buf = (float*)rest;
    float* wx_buf = (float*)(rest + nMD * 4);
    unsigned short* ring = (unsigned short*)(rest + 2 * nMD * 4);
    unsigned int* flags = (unsigned int*)(rest + 2 * nMD * 4 + ringBytes);
    launch_all<float>(x, h0, Wa, ba, Wh, Wx, bb, xb, Wab, Wxb, alpha_buf,
                      wx_buf, ring, flags, out_outs, out_h, stream);
  } else {
    __hip_bfloat16* alpha_buf = (__hip_bfloat16*)rest;
    __hip_bfloat16* wx_buf = (__hip_bfloat16*)(rest + nMD * 2);
    unsigned short* ring = (unsigned short*)(rest + 2 * nMD * 2);
    unsigned int* flags = (unsigned int*)(rest + 2 * nMD * 2 + ringBytes);
    launch_all<__hip_bfloat16>(x, h0, Wa, ba, Wh, Wx, bb, xb, Wab, Wxb,
                               alpha_buf, wx_buf, ring, flags, out_outs, out_h,
                               stream);
  }
}

// Round 7
// 1912.778 us; speedup vs baseline: 5.5610x; 1.7045x over previous
//
#include <hip/hip_runtime.h>
#include <hip/hip_bf16.h>
#include <hip/hip_cooperative_groups.h>

typedef __attribute__((ext_vector_type(8))) short bf16x8;
typedef __attribute__((ext_vector_type(4))) float f32x4;
typedef __attribute__((ext_vector_type(4))) unsigned int u32x4;

#define D_ 1024
#define T_ 1024
#define B_ 8
#define M_ (T_ * B_)

__device__ __forceinline__ float ldv(const float* p) { return *p; }
__device__ __forceinline__ float ldv(const __hip_bfloat16* p) { return __bfloat162float(*p); }
__device__ __forceinline__ void stv(float* p, float v) { *p = v; }
__device__ __forceinline__ void stv(__hip_bfloat16* p, float v) { *p = __float2bfloat16(v); }

// --- MALL-coherent accessors (round-4-proven): sc0 sc1 bypasses L1+L2 ------
// Ring word (u32) = {bf16 payload | tag<<16} in ONE dword: naturally-aligned
// 32-bit accesses are single-copy atomic at every level -> tag/payload can
// never tear; each word is individually correct-or-spin.  No XCD-local mode:
// rounds 5/6 showed the sc0-only fast path consumed stale data (locality
// verdict unreliable); MALL scope is the verified-correct coherence point.
__device__ __forceinline__ u32x4 ld_chunk(const unsigned* p) {
  u32x4 v;
  asm volatile("global_load_dwordx4 %0, %1, off sc0 sc1" : "=v"(v) : "v"(p) : "memory");
  return v;
}
__device__ __forceinline__ void st_word(unsigned* p, unsigned v) {
  asm volatile("global_store_dword %0, %1, off sc0 sc1" :: "v"(p), "v"(v) : "memory");
}
__device__ __forceinline__ void wait_vm0() {
  asm volatile("s_waitcnt vmcnt(0)" ::: "memory");
}

// ---------------------------------------------------------------------------
// f32 -> bf16 bulk convert (8 elems/thread, vectorized)
// ---------------------------------------------------------------------------
__global__ __launch_bounds__(256) void conv_bf16(const float* __restrict__ in,
                                                 __hip_bfloat16* __restrict__ out,
                                                 int n8)
{
  int i = blockIdx.x * blockDim.x + threadIdx.x;
  const int stride = gridDim.x * blockDim.x;
  for (; i < n8; i += stride) {
    const f32x4* p = reinterpret_cast<const f32x4*>(in + (size_t)i * 8);
    f32x4 a = p[0], b = p[1];
    union { bf16x8 v; __hip_bfloat16 e[8]; } u;
#pragma unroll
    for (int j = 0; j < 4; ++j) {
      u.e[j] = __float2bfloat16(a[j]);
      u.e[j + 4] = __float2bfloat16(b[j]);
    }
    *reinterpret_cast<bf16x8*>(out + (size_t)i * 8) = u.v;
  }
}

// ---------------------------------------------------------------------------
// Phase 1: alpha_all = sigmoid(xb @ Wab^T + b_alpha), wx_all = xb @ Wxb^T + b
// (unchanged — verified correct)
// ---------------------------------------------------------------------------
template <typename ST>
__global__ __launch_bounds__(256) void gemm_front(
    const __hip_bfloat16* __restrict__ xb,
    const __hip_bfloat16* __restrict__ Wab,
    const float* __restrict__ ba,
    const __hip_bfloat16* __restrict__ Wxb,
    const float* __restrict__ bbias,
    ST* __restrict__ alpha_out,
    ST* __restrict__ wx_out)
{
  const int tid = threadIdx.x;
  const int lane = tid & 63;
  const int w = tid >> 6;
  const int r = lane & 15;
  const int g = lane >> 4;
  const bool isA = blockIdx.y < 8;
  const int m0 = blockIdx.x * 128 + (w >> 1) * 64;
  const int n0 = (blockIdx.y & 7) * 128 + (w & 1) * 64;
  const __hip_bfloat16* __restrict__ W = isA ? Wab : Wxb;
  ST* __restrict__ outp = isA ? alpha_out : wx_out;

  f32x4 acc[4][4] = {};

  const __hip_bfloat16* aBase = xb + (size_t)(m0 + r) * D_ + g * 8;
  const __hip_bfloat16* bBase = W + (size_t)(n0 + r) * D_ + g * 8;

  for (int k = 0; k < D_; k += 32) {
    bf16x8 a[4], b[4];
#pragma unroll
    for (int mt = 0; mt < 4; ++mt)
      a[mt] = *reinterpret_cast<const bf16x8*>(aBase + (size_t)mt * 16 * D_ + k);
#pragma unroll
    for (int nt = 0; nt < 4; ++nt)
      b[nt] = *reinterpret_cast<const bf16x8*>(bBase + (size_t)nt * 16 * D_ + k);
#pragma unroll
    for (int mt = 0; mt < 4; ++mt)
#pragma unroll
      for (int nt = 0; nt < 4; ++nt)
        acc[mt][nt] = __builtin_amdgcn_mfma_f32_16x16x32_bf16(a[mt], b[nt], acc[mt][nt], 0, 0, 0);
  }

#pragma unroll
  for (int nt = 0; nt < 4; ++nt) {
    const int col = n0 + nt * 16 + r;
    const float bias = isA ? ba[col] : bbias[col];
#pragma unroll
    for (int mt = 0; mt < 4; ++mt) {
      const int row = m0 + mt * 16 + g * 4;
#pragma unroll
      for (int i = 0; i < 4; ++i) {
        float v = acc[mt][nt][i] + bias;
        if (isA) v = 1.0f / (1.0f + expf(-v));
        stv(outp + (size_t)(row + i) * D_ + col, v);
      }
    }
  }
}

// ---------------------------------------------------------------------------
// Phase 2: batch-island scan, word-atomic tag-in-payload, MALL scope only.
// Grid 128 WGs x 256 thr: batch bb = blockIdx&7, slice s = blockIdx>>3.
// Ring word (u32) = {bf16 h | tag<<16}; consumer spins until all 8 tags of
// its 8 columns == t+1.  Depth-2 lap safety: producer overwrites slot parity
// p (tag t+3) only after its step-(t+1) staging observed tags t+2 from all
// slices in each wave's K-quarter (union = all 16), which happens-after
// their reads of tag t+1 from parity p.
// ---------------------------------------------------------------------------
template <typename ST>
__global__ __launch_bounds__(256) void scan_rec(
    const float* __restrict__ h0,
    const float* __restrict__ Wh,
    const ST* __restrict__ alpha_all,
    const ST* __restrict__ wx_all,
    unsigned* __restrict__ ring,     // [2][B][1024] u32 words, memset 0
    float* __restrict__ out_outs,    // [T][B][D] f32
    float* __restrict__ out_h)       // [T+1][B][D] f32
{
  __shared__ __align__(16) unsigned short W_lds[64 * 1024];  // 128 KB, swizzled
  __shared__ __align__(16) unsigned short h_lds[1024];       // h[t] bf16
  __shared__ float C_lds[4][64];                             // per-wave partials

  const int tid = threadIdx.x;
  const int lane = tid & 63;
  const int w = tid >> 6;
  const int r = lane & 15;
  const int g = lane >> 4;
  const int bb = blockIdx.x & 7;   // batch
  const int s = blockIdx.x >> 3;   // col slice
  const int e0 = s * 64;

  // ---- Stage W_h rows e0..e0+63 into LDS as bf16, XOR-swizzled ----
  for (int idx = tid; idx < 64 * 128; idx += 256) {
    const int row = idx >> 7;        // 0..63
    const int k8 = (idx & 127) * 8;  // k chunk start
    const f32x4* p = reinterpret_cast<const f32x4*>(Wh + (size_t)(e0 + row) * D_ + k8);
    f32x4 a = p[0], bv = p[1];
    union { bf16x8 v; __hip_bfloat16 e[8]; } u;
#pragma unroll
    for (int j = 0; j < 4; ++j) {
      u.e[j] = __float2bfloat16(a[j]);
      u.e[j + 4] = __float2bfloat16(bv[j]);
    }
    const unsigned byteoff = ((unsigned)row * 2048u + (unsigned)k8 * 2u) ^ (((unsigned)row & 7u) << 4);
    *reinterpret_cast<bf16x8*>(reinterpret_cast<char*>(W_lds) + byteoff) = u.v;
  }

  // ---- Init: finish threads (wave 0, col e0+tid); publish slot0 tag=1 ----
  float h_f = 0.0f, wx_c = 0.0f, al_c = 0.0f;
  if (tid < 64) {
    const int e = e0 + tid;
    h_f = h0[bb * D_ + e];
    out_h[(size_t)bb * D_ + e] = h_f;
    const unsigned short hb = ((__hip_bfloat16_raw)__float2bfloat16(h_f)).x;
    h_lds[e] = hb;
    st_word(ring + (size_t)bb * 1024 + e, (unsigned)hb | (1u << 16));
    wx_c = ldv(wx_all + (size_t)bb * D_ + e);
    al_c = ldv(alpha_all + (size_t)bb * D_ + e);
  }
  __syncthreads();  // W_lds + h_lds init visible

  for (int t = 0; t < T_; ++t) {
    // ---- stage h[t] quarter: spin on tagged words (lanes 0..31, not own) ----
    const unsigned want = (unsigned)(t + 1);
    const int kk = w * 256 + lane * 8;
    if (lane < 32 && (kk >> 6) != s) {
      const unsigned* cp = ring + ((size_t)(t & 1) * B_ + bb) * 1024 + kk;
      u32x4 A, Bv;
      int bail = 0;
      for (;;) {
        A = ld_chunk(cp);
        Bv = ld_chunk(cp + 4);
        wait_vm0();
        const bool ok = (A[0] >> 16) == want && (A[1] >> 16) == want &&
                        (A[2] >> 16) == want && (A[3] >> 16) == want &&
                        (Bv[0] >> 16) == want && (Bv[1] >> 16) == want &&
                        (Bv[2] >> 16) == want && (Bv[3] >> 16) == want;
        if (__all(ok)) break;
        if (++bail > (1 << 20)) break;  // hang insurance only
      }
      u32x4 hw;
      hw[0] = (A[0] & 0xffffu) | (A[1] << 16);
      hw[1] = (A[2] & 0xffffu) | (A[3] << 16);
      hw[2] = (Bv[0] & 0xffffu) | (Bv[1] << 16);
      hw[3] = (Bv[2] & 0xffffu) | (Bv[3] << 16);
      *reinterpret_cast<u32x4*>(&h_lds[kk]) = hw;
    }
    asm volatile("s_waitcnt lgkmcnt(0)" ::: "memory");
    __builtin_amdgcn_sched_barrier(0);

    // ---- MFMA: y_partial[64] over this wave's K quarter ----
    f32x4 acc[4] = {};
#pragma unroll
    for (int kt = 0; kt < 8; ++kt) {
      const int k = w * 256 + kt * 32 + g * 8;
      bf16x8 afrag = {};
      if (r == 0)
        afrag = *reinterpret_cast<const bf16x8*>(&h_lds[k]);
#pragma unroll
      for (int nt = 0; nt < 4; ++nt) {
        const unsigned row = (unsigned)(nt * 16 + r);
        const unsigned byteoff = (row * 2048u + (unsigned)k * 2u) ^ ((row & 7u) << 4);
        bf16x8 bfrag = *reinterpret_cast<const bf16x8*>(
            reinterpret_cast<const char*>(W_lds) + byteoff);
        acc[nt] = __builtin_amdgcn_mfma_f32_16x16x32_bf16(afrag, bfrag, acc[nt], 0, 0, 0);
      }
    }
    if (g == 0) {
#pragma unroll
      for (int nt = 0; nt < 4; ++nt)
        C_lds[w][nt * 16 + r] = acc[nt][0];
    }
    __syncthreads();

    // ---- finish (wave 0): recurrence; tagged publish FIRST, outputs after ----
    if (tid < 64) {
      const int e = e0 + tid;
      const float y = C_lds[0][tid] + C_lds[1][tid] + C_lds[2][tid] + C_lds[3][tid];
      const float v = tanhf(y + wx_c);
      h_f = al_c * h_f + (1.0f - al_c) * v;
      const unsigned short hb = ((__hip_bfloat16_raw)__float2bfloat16(h_f)).x;
      h_lds[e] = hb;  // own slice short-circuit for next step
      st_word(ring + ((size_t)((t + 1) & 1) * B_ + bb) * 1024 + e,
              (unsigned)hb | ((unsigned)(t + 2) << 16));
      // off-chain work after the publish:
      const float sg = 1.0f / (1.0f + expf(-h_f));
      const float o = h_f * h_f * sg;  // h * silu(h)
      out_h[(size_t)(t + 1) * (B_ * D_) + (size_t)bb * D_ + e] = h_f;
      out_outs[(size_t)t * (B_ * D_) + (size_t)bb * D_ + e] = o;
      if (t + 1 < T_) {
        wx_c = ldv(wx_all + (size_t)((t + 1) * B_ + bb) * D_ + e);
        al_c = ldv(alpha_all + (size_t)((t + 1) * B_ + bb) * D_ + e);
      }
    }
    __syncthreads();  // h_lds(own slice) visible; C_lds reusable
  }
}

// ---------------------------------------------------------------------------
template <typename ST>
static void launch_all(const float* x, const float* h0, const float* Wa,
                       const float* ba, const float* Wh, const float* Wx,
                       const float* bb, __hip_bfloat16* xb, __hip_bfloat16* Wab,
                       __hip_bfloat16* Wxb, ST* alpha_buf, ST* wx_buf,
                       unsigned* ring, float* out_outs, float* out_h,
                       hipStream_t stream)
{
  const size_t ringBytes = (size_t)2 * B_ * 1024 * 4;  // 64 KB
  hipMemsetAsync(ring, 0, ringBytes, stream);
  conv_bf16<<<dim3(2048), dim3(256), 0, stream>>>(x, xb, M_ * D_ / 8);
  conv_bf16<<<dim3(512), dim3(256), 0, stream>>>(Wa, Wab, D_ * D_ / 8);
  conv_bf16<<<dim3(512), dim3(256), 0, stream>>>(Wx, Wxb, D_ * D_ / 8);
  gemm_front<ST><<<dim3(64, 16), dim3(256), 0, stream>>>(xb, Wab, ba, Wxb, bb,
                                                         alpha_buf, wx_buf);
  void* args[] = {(void*)&h0,     (void*)&Wh,   (void*)&alpha_buf,
                  (void*)&wx_buf, (void*)&ring, (void*)&out_outs,
                  (void*)&out_h};
  hipLaunchCooperativeKernel(reinterpret_cast<void*>(&scan_rec<ST>), dim3(128),
                             dim3(256), args, 0, stream);
}

extern "C" void kernel_launch(void* const* d_in, const int* in_sizes, int n_in,
                              void* d_out, int out_size, void* d_ws,
                              size_t ws_size, hipStream_t stream)
{
  const float* x = (const float*)d_in[0];
  const float* h0 = (const float*)d_in[1];
  const float* Wa = (const float*)d_in[2];
  const float* ba = (const float*)d_in[3];
  const float* Wh = (const float*)d_in[4];
  const float* Wx = (const float*)d_in[5];
  const float* bb = (const float*)d_in[6];

  float* out_outs = (float*)d_out;
  float* out_h = out_outs + (size_t)T_ * B_ * D_;

  char* ws = (char*)d_ws;
  const size_t nMD = (size_t)M_ * D_;  // 8,388,608
  const size_t nDD = (size_t)D_ * D_;  // 1,048,576

  __hip_bfloat16* xb = (__hip_bfloat16*)ws;
  __hip_bfloat16* Wab = (__hip_bfloat16*)(ws + nMD * 2);
  __hip_bfloat16* Wxb = (__hip_bfloat16*)(ws + nMD * 2 + nDD * 2);
  char* rest = ws + nMD * 2 + 2 * nDD * 2;

  const size_t ringBytes = (size_t)2 * B_ * 1024 * 4;  // 65536
  const size_t needF32 = (size_t)(rest - ws) + 2 * nMD * 4 + ringBytes;

  if (ws_size >= needF32) {
    float* alpha_buf = (float*)rest;
    float* wx_buf = (float*)(rest + nMD * 4);
    unsigned* ring = (unsigned*)(rest + 2 * nMD * 4);
    launch_all<float>(x, h0, Wa, ba, Wh, Wx, bb, xb, Wab, Wxb, alpha_buf,
                      wx_buf, ring, out_outs, out_h, stream);
  } else {
    __hip_bfloat16* alpha_buf = (__hip_bfloat16*)rest;
    __hip_bfloat16* wx_buf = (__hip_bfloat16*)(rest + nMD * 2);
    unsigned* ring = (unsigned*)(rest + 2 * nMD * 2);
    launch_all<__hip_bfloat16>(x, h0, Wa, ba, Wh, Wx, bb, xb, Wab, Wxb,
                               alpha_buf, wx_buf, ring, out_outs, out_h,
                               stream);
  }
}

// Round 8
// 1911.021 us; speedup vs baseline: 5.5661x; 1.0009x over previous
//
#include <hip/hip_runtime.h>
#include <hip/hip_bf16.h>
#include <hip/hip_cooperative_groups.h>

typedef __attribute__((ext_vector_type(8))) short bf16x8;
typedef __attribute__((ext_vector_type(4))) float f32x4;
typedef __attribute__((ext_vector_type(4))) unsigned int u32x4;

#define D_ 1024
#define T_ 1024
#define B_ 8
#define M_ (T_ * B_)

__device__ __forceinline__ float ldv(const float* p) { return *p; }
__device__ __forceinline__ float ldv(const __hip_bfloat16* p) { return __bfloat162float(*p); }
__device__ __forceinline__ void stv(float* p, float v) { *p = v; }
__device__ __forceinline__ void stv(__hip_bfloat16* p, float v) { *p = __float2bfloat16(v); }

// --- MALL-coherent accessors (round-4/7-proven): sc0 sc1 bypasses L1+L2 ----
__device__ __forceinline__ u32x4 ld_chunk(const unsigned* p) {
  u32x4 v;
  asm volatile("global_load_dwordx4 %0, %1, off sc0 sc1" : "=v"(v) : "v"(p) : "memory");
  return v;
}
__device__ __forceinline__ void st_word(unsigned* p, unsigned v) {
  asm volatile("global_store_dword %0, %1, off sc0 sc1" :: "v"(p), "v"(v) : "memory");
}
__device__ __forceinline__ void wait_vm0() {
  asm volatile("s_waitcnt vmcnt(0)" ::: "memory");
}
// Workgroup barrier WITHOUT the vmcnt(0) drain __syncthreads carries.
// Only LDS hazards exist at our in-loop barriers (C_lds handoff, h_lds own
// slice), so writer-side lgkmcnt(0) + s_barrier suffices; global stores
// (out_h/out_outs/ring) and prefetch loads stay in flight across it.
__device__ __forceinline__ void bar_lds() {
  asm volatile("s_waitcnt lgkmcnt(0)\n\ts_barrier" ::: "memory");
  __builtin_amdgcn_sched_barrier(0);
}

// ---------------------------------------------------------------------------
// f32 -> bf16 bulk convert (8 elems/thread, vectorized)
// ---------------------------------------------------------------------------
__global__ __launch_bounds__(256) void conv_bf16(const float* __restrict__ in,
                                                 __hip_bfloat16* __restrict__ out,
                                                 int n8)
{
  int i = blockIdx.x * blockDim.x + threadIdx.x;
  const int stride = gridDim.x * blockDim.x;
  for (; i < n8; i += stride) {
    const f32x4* p = reinterpret_cast<const f32x4*>(in + (size_t)i * 8);
    f32x4 a = p[0], b = p[1];
    union { bf16x8 v; __hip_bfloat16 e[8]; } u;
#pragma unroll
    for (int j = 0; j < 4; ++j) {
      u.e[j] = __float2bfloat16(a[j]);
      u.e[j + 4] = __float2bfloat16(b[j]);
    }
    *reinterpret_cast<bf16x8*>(out + (size_t)i * 8) = u.v;
  }
}

// ---------------------------------------------------------------------------
// Phase 1: alpha_all = sigmoid(xb @ Wab^T + b_alpha), wx_all = xb @ Wxb^T + b
// (unchanged — verified correct)
// ---------------------------------------------------------------------------
template <typename ST>
__global__ __launch_bounds__(256) void gemm_front(
    const __hip_bfloat16* __restrict__ xb,
    const __hip_bfloat16* __restrict__ Wab,
    const float* __restrict__ ba,
    const __hip_bfloat16* __restrict__ Wxb,
    const float* __restrict__ bbias,
    ST* __restrict__ alpha_out,
    ST* __restrict__ wx_out)
{
  const int tid = threadIdx.x;
  const int lane = tid & 63;
  const int w = tid >> 6;
  const int r = lane & 15;
  const int g = lane >> 4;
  const bool isA = blockIdx.y < 8;
  const int m0 = blockIdx.x * 128 + (w >> 1) * 64;
  const int n0 = (blockIdx.y & 7) * 128 + (w & 1) * 64;
  const __hip_bfloat16* __restrict__ W = isA ? Wab : Wxb;
  ST* __restrict__ outp = isA ? alpha_out : wx_out;

  f32x4 acc[4][4] = {};

  const __hip_bfloat16* aBase = xb + (size_t)(m0 + r) * D_ + g * 8;
  const __hip_bfloat16* bBase = W + (size_t)(n0 + r) * D_ + g * 8;

  for (int k = 0; k < D_; k += 32) {
    bf16x8 a[4], b[4];
#pragma unroll
    for (int mt = 0; mt < 4; ++mt)
      a[mt] = *reinterpret_cast<const bf16x8*>(aBase + (size_t)mt * 16 * D_ + k);
#pragma unroll
    for (int nt = 0; nt < 4; ++nt)
      b[nt] = *reinterpret_cast<const bf16x8*>(bBase + (size_t)nt * 16 * D_ + k);
#pragma unroll
    for (int mt = 0; mt < 4; ++mt)
#pragma unroll
      for (int nt = 0; nt < 4; ++nt)
        acc[mt][nt] = __builtin_amdgcn_mfma_f32_16x16x32_bf16(a[mt], b[nt], acc[mt][nt], 0, 0, 0);
  }

#pragma unroll
  for (int nt = 0; nt < 4; ++nt) {
    const int col = n0 + nt * 16 + r;
    const float bias = isA ? ba[col] : bbias[col];
#pragma unroll
    for (int mt = 0; mt < 4; ++mt) {
      const int row = m0 + mt * 16 + g * 4;
#pragma unroll
      for (int i = 0; i < 4; ++i) {
        float v = acc[mt][nt][i] + bias;
        if (isA) v = 1.0f / (1.0f + expf(-v));
        stv(outp + (size_t)(row + i) * D_ + col, v);
      }
    }
  }
}

// ---------------------------------------------------------------------------
// Phase 2: batch-island scan, word-atomic tag-in-payload, MALL scope only.
// (Protocol identical to round 7.)  Only change: the two in-loop barriers are
// lgkmcnt-only (bar_lds) instead of __syncthreads — __syncthreads' implicit
// vmcnt(0) drain was putting the out-stores + wx/alpha prefetch loads into
// the per-step critical path.
// ---------------------------------------------------------------------------
template <typename ST>
__global__ __launch_bounds__(256) void scan_rec(
    const float* __restrict__ h0,
    const float* __restrict__ Wh,
    const ST* __restrict__ alpha_all,
    const ST* __restrict__ wx_all,
    unsigned* __restrict__ ring,     // [2][B][1024] u32 words, memset 0
    float* __restrict__ out_outs,    // [T][B][D] f32
    float* __restrict__ out_h)       // [T+1][B][D] f32
{
  __shared__ __align__(16) unsigned short W_lds[64 * 1024];  // 128 KB, swizzled
  __shared__ __align__(16) unsigned short h_lds[1024];       // h[t] bf16
  __shared__ float C_lds[4][64];                             // per-wave partials

  const int tid = threadIdx.x;
  const int lane = tid & 63;
  const int w = tid >> 6;
  const int r = lane & 15;
  const int g = lane >> 4;
  const int bb = blockIdx.x & 7;   // batch
  const int s = blockIdx.x >> 3;   // col slice
  const int e0 = s * 64;

  // ---- Stage W_h rows e0..e0+63 into LDS as bf16, XOR-swizzled ----
  for (int idx = tid; idx < 64 * 128; idx += 256) {
    const int row = idx >> 7;        // 0..63
    const int k8 = (idx & 127) * 8;  // k chunk start
    const f32x4* p = reinterpret_cast<const f32x4*>(Wh + (size_t)(e0 + row) * D_ + k8);
    f32x4 a = p[0], bv = p[1];
    union { bf16x8 v; __hip_bfloat16 e[8]; } u;
#pragma unroll
    for (int j = 0; j < 4; ++j) {
      u.e[j] = __float2bfloat16(a[j]);
      u.e[j + 4] = __float2bfloat16(bv[j]);
    }
    const unsigned byteoff = ((unsigned)row * 2048u + (unsigned)k8 * 2u) ^ (((unsigned)row & 7u) << 4);
    *reinterpret_cast<bf16x8*>(reinterpret_cast<char*>(W_lds) + byteoff) = u.v;
  }

  // ---- Init: finish threads (wave 0, col e0+tid); publish slot0 tag=1 ----
  float h_f = 0.0f, wx_c = 0.0f, al_c = 0.0f;
  if (tid < 64) {
    const int e = e0 + tid;
    h_f = h0[bb * D_ + e];
    out_h[(size_t)bb * D_ + e] = h_f;
    const unsigned short hb = ((__hip_bfloat16_raw)__float2bfloat16(h_f)).x;
    h_lds[e] = hb;
    st_word(ring + (size_t)bb * 1024 + e, (unsigned)hb | (1u << 16));
    wx_c = ldv(wx_all + (size_t)bb * D_ + e);
    al_c = ldv(alpha_all + (size_t)bb * D_ + e);
  }
  __syncthreads();  // one-time: W_lds + h_lds init visible (full drain OK)

  for (int t = 0; t < T_; ++t) {
    // ---- stage h[t] quarter: spin on tagged words (lanes 0..31, not own) ----
    const unsigned want = (unsigned)(t + 1);
    const int kk = w * 256 + lane * 8;
    if (lane < 32 && (kk >> 6) != s) {
      const unsigned* cp = ring + ((size_t)(t & 1) * B_ + bb) * 1024 + kk;
      u32x4 A, Bv;
      int bail = 0;
      for (;;) {
        A = ld_chunk(cp);
        Bv = ld_chunk(cp + 4);
        wait_vm0();
        const bool ok = (A[0] >> 16) == want && (A[1] >> 16) == want &&
                        (A[2] >> 16) == want && (A[3] >> 16) == want &&
                        (Bv[0] >> 16) == want && (Bv[1] >> 16) == want &&
                        (Bv[2] >> 16) == want && (Bv[3] >> 16) == want;
        if (__all(ok)) break;
        if (++bail > (1 << 20)) break;  // hang insurance only
      }
      u32x4 hw;
      hw[0] = (A[0] & 0xffffu) | (A[1] << 16);
      hw[1] = (A[2] & 0xffffu) | (A[3] << 16);
      hw[2] = (Bv[0] & 0xffffu) | (Bv[1] << 16);
      hw[3] = (Bv[2] & 0xffffu) | (Bv[3] << 16);
      *reinterpret_cast<u32x4*>(&h_lds[kk]) = hw;
    }
    asm volatile("s_waitcnt lgkmcnt(0)" ::: "memory");
    __builtin_amdgcn_sched_barrier(0);

    // ---- MFMA: y_partial[64] over this wave's K quarter ----
    f32x4 acc[4] = {};
#pragma unroll
    for (int kt = 0; kt < 8; ++kt) {
      const int k = w * 256 + kt * 32 + g * 8;
      bf16x8 afrag = {};
      if (r == 0)
        afrag = *reinterpret_cast<const bf16x8*>(&h_lds[k]);
#pragma unroll
      for (int nt = 0; nt < 4; ++nt) {
        const unsigned row = (unsigned)(nt * 16 + r);
        const unsigned byteoff = (row * 2048u + (unsigned)k * 2u) ^ ((row & 7u) << 4);
        bf16x8 bfrag = *reinterpret_cast<const bf16x8*>(
            reinterpret_cast<const char*>(W_lds) + byteoff);
        acc[nt] = __builtin_amdgcn_mfma_f32_16x16x32_bf16(afrag, bfrag, acc[nt], 0, 0, 0);
      }
    }
    if (g == 0) {
#pragma unroll
      for (int nt = 0; nt < 4; ++nt)
        C_lds[w][nt * 16 + r] = acc[nt][0];
    }
    bar_lds();  // C_lds handoff (LDS-only hazard; no vmcnt drain)

    // ---- finish (wave 0): recurrence; tagged publish FIRST, outputs after ----
    if (tid < 64) {
      const int e = e0 + tid;
      const float y = C_lds[0][tid] + C_lds[1][tid] + C_lds[2][tid] + C_lds[3][tid];
      const float v = tanhf(y + wx_c);
      h_f = al_c * h_f + (1.0f - al_c) * v;
      const unsigned short hb = ((__hip_bfloat16_raw)__float2bfloat16(h_f)).x;
      h_lds[e] = hb;  // own slice short-circuit for next step
      st_word(ring + ((size_t)((t + 1) & 1) * B_ + bb) * 1024 + e,
              (unsigned)hb | ((unsigned)(t + 2) << 16));
      // off-chain work after the publish (floats across the barrier now):
      const float sg = 1.0f / (1.0f + expf(-h_f));
      const float o = h_f * h_f * sg;  // h * silu(h)
      out_h[(size_t)(t + 1) * (B_ * D_) + (size_t)bb * D_ + e] = h_f;
      out_outs[(size_t)t * (B_ * D_) + (size_t)bb * D_ + e] = o;
      if (t + 1 < T_) {
        wx_c = ldv(wx_all + (size_t)((t + 1) * B_ + bb) * D_ + e);
        al_c = ldv(alpha_all + (size_t)((t + 1) * B_ + bb) * D_ + e);
      }
    }
    bar_lds();  // h_lds(own slice) visible; C_lds reusable (LDS-only hazard)
  }
}

// ---------------------------------------------------------------------------
template <typename ST>
static void launch_all(const float* x, const float* h0, const float* Wa,
                       const float* ba, const float* Wh, const float* Wx,
                       const float* bb, __hip_bfloat16* xb, __hip_bfloat16* Wab,
                       __hip_bfloat16* Wxb, ST* alpha_buf, ST* wx_buf,
                       unsigned* ring, float* out_outs, float* out_h,
                       hipStream_t stream)
{
  const size_t ringBytes = (size_t)2 * B_ * 1024 * 4;  // 64 KB
  hipMemsetAsync(ring, 0, ringBytes, stream);
  conv_bf16<<<dim3(2048), dim3(256), 0, stream>>>(x, xb, M_ * D_ / 8);
  conv_bf16<<<dim3(512), dim3(256), 0, stream>>>(Wa, Wab, D_ * D_ / 8);
  conv_bf16<<<dim3(512), dim3(256), 0, stream>>>(Wx, Wxb, D_ * D_ / 8);
  gemm_front<ST><<<dim3(64, 16), dim3(256), 0, stream>>>(xb, Wab, ba, Wxb, bb,
                                                         alpha_buf, wx_buf);
  void* args[] = {(void*)&h0,     (void*)&Wh,   (void*)&alpha_buf,
                  (void*)&wx_buf, (void*)&ring, (void*)&out_outs,
                  (void*)&out_h};
  hipLaunchCooperativeKernel(reinterpret_cast<void*>(&scan_rec<ST>), dim3(128),
                             dim3(256), args, 0, stream);
}

extern "C" void kernel_launch(void* const* d_in, const int* in_sizes, int n_in,
                              void* d_out, int out_size, void* d_ws,
                              size_t ws_size, hipStream_t stream)
{
  const float* x = (const float*)d_in[0];
  const float* h0 = (const float*)d_in[1];
  const float* Wa = (const float*)d_in[2];
  const float* ba = (const float*)d_in[3];
  const float* Wh = (const float*)d_in[4];
  const float* Wx = (const float*)d_in[5];
  const float* bb = (const float*)d_in[6];

  float* out_outs = (float*)d_out;
  float* out_h = out_outs + (size_t)T_ * B_ * D_;

  char* ws = (char*)d_ws;
  const size_t nMD = (size_t)M_ * D_;  // 8,388,608
  const size_t nDD = (size_t)D_ * D_;  // 1,048,576

  __hip_bfloat16* xb = (__hip_bfloat16*)ws;
  __hip_bfloat16* Wab = (__hip_bfloat16*)(ws + nMD * 2);
  __hip_bfloat16* Wxb = (__hip_bfloat16*)(ws + nMD * 2 + nDD * 2);
  char* rest = ws + nMD * 2 + 2 * nDD * 2;

  const size_t ringBytes = (size_t)2 * B_ * 1024 * 4;  // 65536
  const size_t needF32 = (size_t)(rest - ws) + 2 * nMD * 4 + ringBytes;

  if (ws_size >= needF32) {
    float* alpha_buf = (float*)rest;
    float* wx_buf = (float*)(rest + nMD * 4);
    unsigned* ring = (unsigned*)(rest + 2 * nMD * 4);
    launch_all<float>(x, h0, Wa, ba, Wh, Wx, bb, xb, Wab, Wxb, alpha_buf,
                      wx_buf, ring, out_outs, out_h, stream);
  } else {
    __hip_bfloat16* alpha_buf = (__hip_bfloat16*)rest;
    __hip_bfloat16* wx_buf = (__hip_bfloat16*)(rest + nMD * 2);
    unsigned* ring = (unsigned*)(rest + 2 * nMD * 2);
    launch_all<__hip_bfloat16>(x, h0, Wa, ba, Wh, Wx, bb, xb, Wab, Wxb,
                               alpha_buf, wx_buf, ring, out_outs, out_h,
                               stream);
  }
}